// Round 1
// 418.620 us; speedup vs baseline: 1.0950x; 1.0950x over previous
//
#include <hip/hip_runtime.h>

typedef float v4f __attribute__((ext_vector_type(4)));

// Problem constants
#define B_ 128
#define T_ 197
#define D_ 768
#define E_ 8
#define R_ 8
#define O_ 2304

// d_out flat layout (fp32 elements), in reference return order
#define NWU      (128LL * 197LL * 2304LL)      // weighted_update
#define OFF_RL   (NWU)                          // router_logits: 128*8
#define OFF_SEL  (OFF_RL + 1024LL)              // selected_experts: 128 (as float)
#define OFF_EW   (OFF_SEL + 128LL)              // expert_weights: 128*8
#define OFF_IMP  (OFF_EW + 1024LL)              // importance: 8
#define OFF_LOAD (OFF_IMP + 8LL)                // load: 8

// ---------------------------------------------------------------------------
// Kernel 1: partial token sums over T-chunks, float4-vectorized.
// partials live in the WU region of d_out (consumed by `route` before
// fused_lora overwrites the region).  part[(b*4+c)*768 + d]
// Also zero-inits the importance/load accumulators (16 floats) so `route`
// can atomically accumulate into them (stream order guarantees visibility).
// ---------------------------------------------------------------------------
__global__ void pool_partial(const float* __restrict__ tokens,
                             float* __restrict__ out) {
    int c   = blockIdx.x;          // 0..3
    int b   = blockIdx.y;          // 0..127
    int tid = threadIdx.x;         // 0..191  (float4 column)
    if (c == 0 && b == 0 && tid < 16) out[OFF_IMP + tid] = 0.0f;
    int t0 = c * 50;
    int t1 = t0 + 50; if (t1 > T_) t1 = T_;
    const float4* tp = (const float4*)(tokens + (long long)b * T_ * D_);
    float4 acc; acc.x = 0.f; acc.y = 0.f; acc.z = 0.f; acc.w = 0.f;
    for (int t = t0; t < t1; ++t) {
        float4 v = tp[t * 192 + tid];
        acc.x += v.x; acc.y += v.y; acc.z += v.z; acc.w += v.w;
    }
    ((float4*)out)[(long long)(b * 4 + c) * 192 + tid] = acc;
}

// ---------------------------------------------------------------------------
// Kernel 2: routing + stats.  One block per batch row.
// stats (importance/load) folded in via device-scope atomicAdd — removes
// the former single-block `stats` kernel (a full-device serialization point).
// ---------------------------------------------------------------------------
__global__ void route(const float* __restrict__ part,
                      const float* __restrict__ w_gate,
                      float* __restrict__ out) {
    __shared__ float pooled[768];
    __shared__ float psum[64];
    __shared__ float logits[8];
    __shared__ int   sel_s;
    __shared__ float top1_s;
    __shared__ float m_s, inv_s;

    int b   = blockIdx.x;
    int tid = threadIdx.x;

    #pragma unroll
    for (int j = 0; j < 3; ++j) {
        int d = tid + j * 256;
        float s = part[(long long)(b * 4 + 0) * D_ + d]
                + part[(long long)(b * 4 + 1) * D_ + d]
                + part[(long long)(b * 4 + 2) * D_ + d]
                + part[(long long)(b * 4 + 3) * D_ + d];
        pooled[d] = s * (1.0f / 197.0f);
    }
    __syncthreads();

    if (tid < 64) {
        int e = tid & 7;
        int p = tid >> 3;
        float s = 0.f;
        int d0 = p * 96;
        for (int d = d0; d < d0 + 96; ++d) s += pooled[d] * w_gate[d * 8 + e];
        psum[tid] = s;
    }
    __syncthreads();

    if (tid < 8) {
        float s = 0.f;
        #pragma unroll
        for (int p = 0; p < 8; ++p) s += psum[p * 8 + tid];
        logits[tid] = s;
        out[OFF_RL + (long long)b * 8 + tid] = s;
    }
    __syncthreads();

    if (tid == 0) {
        float m = logits[0];
        int sel = 0;
        #pragma unroll
        for (int e = 1; e < 8; ++e)
            if (logits[e] > m) { m = logits[e]; sel = e; }   // first max wins
        float den = 0.f;
        #pragma unroll
        for (int e = 0; e < 8; ++e) den += expf(logits[e] - m);
        float t1v = 1.0f / den;
        sel_s  = sel;
        top1_s = t1v;
        m_s    = m;
        inv_s  = t1v;
        out[OFF_SEL + b] = (float)sel;
        atomicAdd(&out[OFF_IMP + sel], t1v);     // importance[sel] += top1
    }
    __syncthreads();

    if (tid < 8) {
        out[OFF_EW + (long long)b * 8 + tid] = (tid == sel_s) ? top1_s : 0.0f;
        // load[e] += softmax(logits)[e]
        atomicAdd(&out[OFF_LOAD + tid], expf(logits[tid] - m_s) * inv_s);
    }
}

// ---------------------------------------------------------------------------
// Kernel 3: fused  h = (tokens @ A[sel]) * gs  →  LDS  →  wu = h @ Bw[sel].
// h never touches HBM.  LDS budget: Bw_s 72 KB + h_s 1.6 KB = 75.3 KB
// → 2 blocks/CU, so one resident block's token-read phase overlaps the
// other's 232 MB write phase.
// Staging overlay: A^T occupies Bw_s[0:6144] during phase 1; Bw rows'
// upper 48 KB (float4 idx 1536..4607) is prefetched in phase 0, only the
// lower 24 KB is staged in phase 2 (all L2-hot: lora_b is 590 KB total).
// Phase 3 processes 4 rows per Bw pass → LDS read traffic /4 (1.86 GB →
// 465 MB), leaving the HBM write pipe as the only bottleneck.
// ---------------------------------------------------------------------------
__global__ void __launch_bounds__(256, 2)
fused_lora(const float* __restrict__ tokens,
           const float* __restrict__ lora_a,
           const float* __restrict__ lora_b,
           const float* __restrict__ scaling,
           const float* __restrict__ outc,
           float* __restrict__ out) {
    __shared__ __align__(16) float Bw_s[8 * 2304];   // 72 KB (first 24 KB doubles as As)
    __shared__ __align__(16) float h_s[50 * 8];      // 1.6 KB

    int chunk = blockIdx.x;
    int b     = blockIdx.y;
    int tid   = threadIdx.x;

    int   sel  = (int)outc[OFF_SEL + b];
    float top1 = outc[OFF_EW + (long long)b * 8 + sel];
    float gs   = scaling[sel] * top1;

    // ---- Phase 0: stage A[sel] ([d][r] layout) transposed into As[r][d]
    //      = Bw_s[r*768+d], and prefetch the upper 48 KB of Bw[sel].
    const float4* A4 = (const float4*)(lora_a + (long long)sel * 768 * 8);
    for (int f = tid; f < 1536; f += 256) {
        float4 g = A4[f];
        int d  = f >> 1;
        int r0 = (f & 1) * 4;
        Bw_s[(r0 + 0) * 768 + d] = g.x;
        Bw_s[(r0 + 1) * 768 + d] = g.y;
        Bw_s[(r0 + 2) * 768 + d] = g.z;
        Bw_s[(r0 + 3) * 768 + d] = g.w;
    }
    const float4* Bw4g = (const float4*)(lora_b + (long long)sel * 8 * 2304);
    float4*       Bw4s = (float4*)Bw_s;
    for (int i = 1536 + tid; i < 4608; i += 256) Bw4s[i] = Bw4g[i];
    __syncthreads();

    int wave = tid >> 6;
    int lane = tid & 63;
    int t0 = chunk * 50;
    int t1 = t0 + 50; if (t1 > T_) t1 = T_;
    int nrows = t1 - t0;
    int rpw = (nrows + 3) >> 2;
    int ts  = t0 + wave * rpw;
    int te  = ts + rpw; if (te > t1) te = t1;

    // ---- Phase 1: h rows → LDS (wave-per-row, shuffle reduce)
    for (int t = ts; t < te; ++t) {
        const float4* tok4 = (const float4*)(tokens + ((long long)b * T_ + t) * D_);
        float acc[8];
        #pragma unroll
        for (int r = 0; r < 8; ++r) acc[r] = 0.f;

        #pragma unroll
        for (int k = 0; k < 3; ++k) {
            int d4 = lane + 64 * k;
            float4 tv = tok4[d4];
            #pragma unroll
            for (int r = 0; r < 8; ++r) {
                float4 ar = *(const float4*)(Bw_s + r * 768 + d4 * 4);
                acc[r] += tv.x * ar.x + tv.y * ar.y + tv.z * ar.z + tv.w * ar.w;
            }
        }

        #pragma unroll
        for (int off = 32; off > 0; off >>= 1) {
            #pragma unroll
            for (int r = 0; r < 8; ++r)
                acc[r] += __shfl_xor(acc[r], off, 64);
        }

        if (lane == 0) {
            #pragma unroll
            for (int r = 0; r < 8; ++r) h_s[(t - t0) * 8 + r] = acc[r] * gs;
        }
    }
    __syncthreads();

    // ---- Phase 2: stage the lower 24 KB of Bw[sel] (overwrites As)
    for (int i = tid; i < 1536; i += 256) Bw4s[i] = Bw4g[i];
    __syncthreads();

    // ---- Phase 3: weighted_update, 4 rows per pass over Bw
    for (int tb = ts; tb < te; tb += 4) {
        int nr = te - tb; if (nr > 4) nr = 4;

        float hreg[4][8];
        #pragma unroll
        for (int r = 0; r < 4; ++r) {
            if (r < nr) {
                #pragma unroll
                for (int j = 0; j < 8; ++j)
                    hreg[r][j] = h_s[(tb - t0 + r) * 8 + j];
            }
        }

        #pragma unroll
        for (int k = 0; k < 9; ++k) {
            int o4 = lane + 64 * k;
            v4f accv[4];
            #pragma unroll
            for (int r = 0; r < 4; ++r) {
                accv[r].x = 0.f; accv[r].y = 0.f; accv[r].z = 0.f; accv[r].w = 0.f;
            }
            #pragma unroll
            for (int j = 0; j < 8; ++j) {
                v4f bv = ((const v4f*)Bw_s)[j * 576 + o4];
                #pragma unroll
                for (int r = 0; r < 4; ++r) {
                    if (r < nr) accv[r] += hreg[r][j] * bv;
                }
            }
            #pragma unroll
            for (int r = 0; r < 4; ++r) {
                if (r < nr) {
                    v4f* outrow = (v4f*)(out + ((long long)b * T_ + (tb + r)) * O_);
                    __builtin_nontemporal_store(accv[r], &outrow[o4]);
                }
            }
        }
    }
}

// ---------------------------------------------------------------------------
extern "C" void kernel_launch(void* const* d_in, const int* in_sizes, int n_in,
                              void* d_out, int out_size, void* d_ws, size_t ws_size,
                              hipStream_t stream) {
    const float* tokens  = (const float*)d_in[0];
    const float* w_gate  = (const float*)d_in[1];
    const float* lora_a  = (const float*)d_in[2];
    const float* lora_b  = (const float*)d_in[3];
    const float* scaling = (const float*)d_in[4];
    float* out = (float*)d_out;

    pool_partial<<<dim3(4, 128), 192, 0, stream>>>(tokens, out);
    route<<<128, 256, 0, stream>>>(out, w_gate, out);
    fused_lora<<<dim3(4, 128), 256, 0, stream>>>(tokens, lora_a, lora_b, scaling, out, out);
}